// Round 5
// baseline (245.126 us; speedup 1.0000x reference)
//
#include <hip/hip_runtime.h>

constexpr int FRAME_LEN = 130;   // floats per frame
constexpr int HALF      = 65;    // floats per hand block
constexpr int BLOCK     = 256;   // threads per block
constexpr int FPB       = 32;    // frames per block
constexpr int CHUNK_F   = FPB * FRAME_LEN;     // 4160 floats
constexpr int CHUNK_F2  = CHUNK_F / 2;         // 2080 float2 = 8*256 + 32

// frame = idx / 130 for idx < 7825 via magic multiply
__device__ __forceinline__ int div130(int idx) {
    return (int)(((unsigned)idx * 8067u) >> 20);
}

__device__ __forceinline__ bool skip_pred(float h0, float p0, float h1, float p1) {
    const bool nan0 = (h0 != h0);
    const bool nan1 = (h1 != h1);
    const bool no_nan = !nan0 && !nan1;
    const bool eq = (h0 == h1);
    return (h1 > h0) ||
           (nan0 && nan1) ||
           (nan0 && (h1 == 1.0f)) ||
           (nan1 && (h0 == 0.0f)) ||
           (no_nan && eq && (h0 == 0.0f) && (p0 > p1)) ||
           (no_nan && eq && (h0 == 1.0f) && (p0 < p1));
}

// One output float2 (chunk-local float2 index g), fully branchless.
// idx = 2g is even => jj in {0..128}, so jj and jj+1 are always in the
// same frame; each element's source is sj = jj + (skip?0 : jj<65?+65:-65).
__device__ __forceinline__ float2 make_out2(const float* __restrict__ Xb,
                                            unsigned mask, int g) {
    const int idx = 2 * g;
    const int fl  = div130(idx);
    const int jj  = idx - fl * FRAME_LEN;
    const bool sk = (mask >> fl) & 1u;
    const int d0  = sk ? 0 : (jj     < HALF ?  HALF : -HALF);
    const int d1  = sk ? 0 : (jj + 1 < HALF ?  HALF : -HALF);
    const int fbase = fl * FRAME_LEN;
    float2 r;
    r.x = Xb[fbase + jj     + d0];
    r.y = Xb[fbase + jj + 1 + d1];
    return r;
}

__global__ __launch_bounds__(BLOCK, 8)   // 8 blocks/CU
void hand_sorter_kernel(const float* __restrict__ X, float* __restrict__ out,
                        int n_frames) {
    const int t = threadIdx.x;
    const long long frame0 = (long long)blockIdx.x * FPB;
    const long long rem = (long long)n_frames - frame0;
    const int frames_here = rem < (long long)FPB ? (int)rem : FPB;
    const long long base = frame0 * (long long)FRAME_LEN;
    const float* __restrict__ Xb = X + base;
    float* __restrict__ Ob = out + base;

    if (frames_here == FPB) {
        // ---- per-wave skip mask: lanes 0..31 test frame==lane; no LDS, no barrier
        const int lane = t & 63;
        bool pred = false;
        if (lane < FPB) {
            const float* fr = Xb + lane * FRAME_LEN;
            const float2 a = *(const float2*)fr;          // h0, p0
            const float2 b = *(const float2*)(fr + 64);   // -, h1
            const float2 c = *(const float2*)(fr + 66);   // p1, -
            pred = skip_pred(a.x, a.y, b.y, c.x);
        }
        const unsigned mask = (unsigned)__ballot(pred);

        float2* __restrict__ Ov = (float2*)Ob;

        // ---- 8 uniform iterations + 1 predicated tail; zero divergence ----
#pragma unroll
        for (int k = 0; k < 8; ++k) {
            const int g = t + k * 256;
            Ov[g] = make_out2(Xb, mask, g);
        }
        {
            const int g = t + 2048;
            if (g < CHUNK_F2) Ov[g] = make_out2(Xb, mask, g);
        }
    } else {
        // ---- generic tail path (never taken for bench shape) ----
        const int nf = frames_here * FRAME_LEN;
        for (int i = t; i < nf; i += BLOCK) {
            const int fle = div130(i);
            const int je  = i - fle * FRAME_LEN;
            const float* fr = Xb + fle * FRAME_LEN;
            const bool sk = skip_pred(fr[0], fr[1], fr[HALF], fr[HALF + 1]);
            int sj = je + (sk ? 0 : (je < HALF ? HALF : -HALF));
            Ob[i] = fr[sj];
        }
    }
}

extern "C" void kernel_launch(void* const* d_in, const int* in_sizes, int n_in,
                              void* d_out, int out_size, void* d_ws, size_t ws_size,
                              hipStream_t stream) {
    const float* X = (const float*)d_in[0];
    float* out = (float*)d_out;
    const int n_frames = in_sizes[0] / FRAME_LEN;   // 262144
    const int n_blocks = (n_frames + FPB - 1) / FPB;
    hand_sorter_kernel<<<n_blocks, BLOCK, 0, stream>>>(X, out, n_frames);
}

// Round 6
// 243.857 us; speedup vs baseline: 1.0052x; 1.0052x over previous
//
#include <hip/hip_runtime.h>

constexpr int FRAME_LEN = 130;   // floats per frame
constexpr int HALF      = 65;    // floats per hand block
constexpr int BLOCK     = 256;   // threads per block
constexpr int FPB       = 32;    // frames per block
constexpr int CHUNK_F   = FPB * FRAME_LEN;   // 4160 floats
constexpr int CHUNK_V4  = CHUNK_F / 4;       // 1040 vec4 = 4*256 + 16

typedef float v4f __attribute__((ext_vector_type(4)));

// frame = idx / 130 for idx < 7825 via magic multiply
__device__ __forceinline__ int div130(int idx) {
    return (int)(((unsigned)idx * 8067u) >> 20);
}

__device__ __forceinline__ bool skip_pred(float h0, float p0, float h1, float p1) {
    const bool nan0 = (h0 != h0);
    const bool nan1 = (h1 != h1);
    const bool no_nan = !nan0 && !nan1;
    const bool eq = (h0 == h1);
    return (h1 > h0) ||
           (nan0 && nan1) ||
           (nan0 && (h1 == 1.0f)) ||
           (nan1 && (h0 == 0.0f)) ||
           (no_nan && eq && (h0 == 0.0f) && (p0 > p1)) ||
           (no_nan && eq && (h0 == 1.0f) && (p0 < p1));
}

__global__ __launch_bounds__(BLOCK, 4)   // <=128 VGPR: room for 10 vec4 in flight
void hand_sorter_kernel(const float* __restrict__ X, float* __restrict__ out,
                        int n_frames) {
    const int t = threadIdx.x;
    const long long frame0 = (long long)blockIdx.x * FPB;
    const long long rem = (long long)n_frames - frame0;
    const int frames_here = rem < (long long)FPB ? (int)rem : FPB;
    const long long base = frame0 * (long long)FRAME_LEN;
    const float* __restrict__ Xb = X + base;
    float* __restrict__ Ob = out + base;

    if (frames_here == FPB) {
        // ---- per-wave skip mask: lanes 0..31 test frame==lane; no LDS/barrier
        const int lane = t & 63;
        bool pred = false;
        if (lane < FPB) {
            const float* fr = Xb + lane * FRAME_LEN;
            const float2 a = *(const float2*)fr;          // h0, p0
            const float2 b = *(const float2*)(fr + 64);   // -, h1
            const float2 c = *(const float2*)(fr + 66);   // p1, -
            pred = skip_pred(a.x, a.y, b.y, c.x);
        }
        const unsigned mask = (unsigned)__ballot(pred);

        const v4f* __restrict__ Xv = (const v4f*)Xb;
        v4f* __restrict__ Ov = (v4f*)Ob;

        // ================= phase 1: issue ALL aligned loads =================
        // out vec4 i <- funnel shift of input vec4s a=s>>2, a+1 where
        // s = 4i + (skip?0 : jj<65?+65:-65).  All addresses clamped to the
        // chunk so loads are unconditionally safe (boundary lanes re-gather
        // in phase 2 and ignore these values).
        v4f va[5], vb[5];
#pragma unroll
        for (int k = 0; k < 5; ++k) {
            const int i0 = t + k * 256;
            const int i  = (k < 4 || i0 < CHUNK_V4) ? i0 : 0;  // safe for t>=16
            const int idx = 4 * i;
            const int fl  = div130(idx);
            const int jj  = idx - fl * FRAME_LEN;
            const bool skipf = (mask >> fl) & 1u;
            const bool lo = (jj < HALF);
            int s = idx + (skipf ? 0 : (lo ? HALF : -HALF));
            int a = s >> 2;
            if (a > CHUNK_V4 - 1) a = CHUNK_V4 - 1;
            int a1 = a + 1;
            if (a1 > CHUNK_V4 - 1) a1 = CHUNK_V4 - 1;
            va[k] = Xv[a];
            vb[k] = Xv[a1];
        }

        // ================= phase 2: combine + store =================
#pragma unroll
        for (int k = 0; k < 5; ++k) {
            const int i = t + k * 256;
            if (k == 4 && i >= CHUNK_V4) continue;
            const int idx = 4 * i;
            const int fl  = div130(idx);
            const int jj  = idx - fl * FRAME_LEN;
            const bool fast = (jj <= FRAME_LEN - 4) && (jj < HALF - 3 || jj >= HALF);
            v4f r;
            if (fast) {
                const bool skipf = (mask >> fl) & 1u;
                const bool lo = (jj < HALF);
                v4f f1; f1.x = va[k].y; f1.y = va[k].z; f1.z = va[k].w; f1.w = vb[k].x; // s&3==1
                v4f f3; f3.x = va[k].w; f3.y = vb[k].x; f3.z = vb[k].y; f3.w = vb[k].z; // s&3==3
                const v4f swp = lo ? f1 : f3;
                r = skipf ? va[k] : swp;       // s&3==0: aligned vec4 itself
            } else {
                // frame-/half-boundary straddling vec4 (~8% of lanes)
#pragma unroll
                for (int e = 0; e < 4; ++e) {
                    const int ide = idx + e;
                    const int fle = div130(ide);
                    const int je  = ide - fle * FRAME_LEN;
                    const bool sk = (mask >> fle) & 1u;
                    const int sj = je + (sk ? 0 : (je < HALF ? HALF : -HALF));
                    ((float*)&r)[e] = Xb[fle * FRAME_LEN + sj];
                }
            }
            Ov[i] = r;
        }
    } else {
        // ---- generic tail path (never taken for bench shape) ----
        const int nf = frames_here * FRAME_LEN;
        for (int i = t; i < nf; i += BLOCK) {
            const int fle = div130(i);
            const int je  = i - fle * FRAME_LEN;
            const float* fr = Xb + fle * FRAME_LEN;
            const bool sk = skip_pred(fr[0], fr[1], fr[HALF], fr[HALF + 1]);
            int sj = je + (sk ? 0 : (je < HALF ? HALF : -HALF));
            Ob[i] = fr[sj];
        }
    }
}

extern "C" void kernel_launch(void* const* d_in, const int* in_sizes, int n_in,
                              void* d_out, int out_size, void* d_ws, size_t ws_size,
                              hipStream_t stream) {
    const float* X = (const float*)d_in[0];
    float* out = (float*)d_out;
    const int n_frames = in_sizes[0] / FRAME_LEN;   // 262144
    const int n_blocks = (n_frames + FPB - 1) / FPB;
    hand_sorter_kernel<<<n_blocks, BLOCK, 0, stream>>>(X, out, n_frames);
}

// Round 7
// 241.486 us; speedup vs baseline: 1.0151x; 1.0098x over previous
//
#include <hip/hip_runtime.h>

constexpr int FRAME_LEN = 130;   // floats per frame
constexpr int HALF      = 65;    // floats per hand block
constexpr int BLOCK     = 256;   // threads per block
constexpr int FPB       = 32;    // frames per block
constexpr int CHUNK_F   = FPB * FRAME_LEN;   // 4160 floats
constexpr int CHUNK_V4  = CHUNK_F / 4;       // 1040 vec4 = 4*256 + 16

typedef float v4f __attribute__((ext_vector_type(4)));

// frame = idx / 130 for idx < 7825 via magic multiply
__device__ __forceinline__ int div130(int idx) {
    return (int)(((unsigned)idx * 8067u) >> 20);
}

__device__ __forceinline__ bool skip_pred(float h0, float p0, float h1, float p1) {
    const bool nan0 = (h0 != h0);
    const bool nan1 = (h1 != h1);
    const bool no_nan = !nan0 && !nan1;
    const bool eq = (h0 == h1);
    return (h1 > h0) ||
           (nan0 && nan1) ||
           (nan0 && (h1 == 1.0f)) ||
           (nan1 && (h0 == 0.0f)) ||
           (no_nan && eq && (h0 == 0.0f) && (p0 > p1)) ||
           (no_nan && eq && (h0 == 1.0f) && (p0 < p1));
}

__global__ __launch_bounds__(BLOCK, 4)   // <=128 VGPR: room for 10 vec4 in flight
void hand_sorter_kernel(const float* __restrict__ X, float* __restrict__ out,
                        int n_frames) {
    const int t = threadIdx.x;
    const long long frame0 = (long long)blockIdx.x * FPB;
    const long long rem = (long long)n_frames - frame0;
    const int frames_here = rem < (long long)FPB ? (int)rem : FPB;
    const long long base = frame0 * (long long)FRAME_LEN;
    const float* __restrict__ Xb = X + base;
    float* __restrict__ Ob = out + base;

    if (frames_here == FPB) {
        // ---- per-wave skip mask: lanes 0..31 test frame==lane; no LDS/barrier
        const int lane = t & 63;
        bool pred = false;
        if (lane < FPB) {
            const float* fr = Xb + lane * FRAME_LEN;
            const v4f a = *(const v4f*)fr;          // h0=a.x  p0=a.y
            const v4f b = *(const v4f*)(fr + 64);   // h1=b.y  p1=b.z
            pred = skip_pred(a.x, a.y, b.y, b.z);
        }
        const unsigned mask = (unsigned)__ballot(pred);

        const v4f* __restrict__ Xv = (const v4f*)Xb;
        v4f* __restrict__ Ov = (v4f*)Ob;

        // ================= phase 1: issue ALL aligned loads =================
        // out vec4 i <- funnel shift of input vec4s a=s>>2, a+1 where
        // s = 4i + (skip?0 : jj<65?+65:-65).  Addresses clamped to the chunk
        // so every load is unconditionally safe (boundary lanes re-gather in
        // phase 2 and ignore these values).
        v4f va0, va1, va2, va3, va4, vb0, vb1, vb2, vb3, vb4;
#define LOAD_PAIR(K, VA, VB)                                              \
        {                                                                 \
            const int i0 = t + (K) * 256;                                 \
            const int i  = ((K) < 4 || i0 < CHUNK_V4) ? i0 : 0;           \
            const int idx = 4 * i;                                        \
            const int fl  = div130(idx);                                  \
            const int jj  = idx - fl * FRAME_LEN;                         \
            const bool skipf = (mask >> fl) & 1u;                         \
            const bool lo = (jj < HALF);                                  \
            int s = idx + (skipf ? 0 : (lo ? HALF : -HALF));              \
            int a = s >> 2;                                               \
            if (a > CHUNK_V4 - 1) a = CHUNK_V4 - 1;                       \
            int a1 = a + 1;                                               \
            if (a1 > CHUNK_V4 - 1) a1 = CHUNK_V4 - 1;                     \
            VA = Xv[a];                                                   \
            VB = Xv[a1];                                                  \
        }
        LOAD_PAIR(0, va0, vb0)
        LOAD_PAIR(1, va1, vb1)
        LOAD_PAIR(2, va2, vb2)
        LOAD_PAIR(3, va3, vb3)
        LOAD_PAIR(4, va4, vb4)
#undef LOAD_PAIR

        // Pin all ten vec4s live here: forces the compiler to issue all 10
        // global_load_dwordx4 before any consumer (real MLP, 40 data VGPRs).
        asm volatile("" : "+v"(va0), "+v"(va1), "+v"(va2), "+v"(va3), "+v"(va4),
                          "+v"(vb0), "+v"(vb1), "+v"(vb2), "+v"(vb3), "+v"(vb4));

        // ================= phase 2: combine + store =================
#define EMIT(K, VA, VB)                                                   \
        {                                                                 \
            const int i = t + (K) * 256;                                  \
            if ((K) < 4 || i < CHUNK_V4) {                                \
                const int idx = 4 * i;                                    \
                const int fl  = div130(idx);                              \
                const int jj  = idx - fl * FRAME_LEN;                     \
                const bool fast = (jj <= FRAME_LEN - 4) &&                \
                                  (jj < HALF - 3 || jj >= HALF);          \
                v4f r;                                                    \
                if (fast) {                                               \
                    const bool skipf = (mask >> fl) & 1u;                 \
                    const bool lo = (jj < HALF);                          \
                    v4f f1; f1.x = VA.y; f1.y = VA.z; f1.z = VA.w; f1.w = VB.x; \
                    v4f f3; f3.x = VA.w; f3.y = VB.x; f3.z = VB.y; f3.w = VB.z; \
                    const v4f swp = lo ? f1 : f3;                         \
                    r = skipf ? VA : swp;                                 \
                } else {                                                  \
                    _Pragma("unroll")                                     \
                    for (int e = 0; e < 4; ++e) {                         \
                        const int ide = idx + e;                          \
                        const int fle = div130(ide);                      \
                        const int je  = ide - fle * FRAME_LEN;            \
                        const bool sk = (mask >> fle) & 1u;               \
                        const int sj = je + (sk ? 0 : (je < HALF ? HALF : -HALF)); \
                        ((float*)&r)[e] = Xb[fle * FRAME_LEN + sj];       \
                    }                                                     \
                }                                                         \
                Ov[i] = r;                                                \
            }                                                             \
        }
        EMIT(0, va0, vb0)
        EMIT(1, va1, vb1)
        EMIT(2, va2, vb2)
        EMIT(3, va3, vb3)
        EMIT(4, va4, vb4)
#undef EMIT
    } else {
        // ---- generic tail path (never taken for bench shape) ----
        const int nf = frames_here * FRAME_LEN;
        for (int i = t; i < nf; i += BLOCK) {
            const int fle = div130(i);
            const int je  = i - fle * FRAME_LEN;
            const float* fr = Xb + fle * FRAME_LEN;
            const bool sk = skip_pred(fr[0], fr[1], fr[HALF], fr[HALF + 1]);
            int sj = je + (sk ? 0 : (je < HALF ? HALF : -HALF));
            Ob[i] = fr[sj];
        }
    }
}

extern "C" void kernel_launch(void* const* d_in, const int* in_sizes, int n_in,
                              void* d_out, int out_size, void* d_ws, size_t ws_size,
                              hipStream_t stream) {
    const float* X = (const float*)d_in[0];
    float* out = (float*)d_out;
    const int n_frames = in_sizes[0] / FRAME_LEN;   // 262144
    const int n_blocks = (n_frames + FPB - 1) / FPB;
    hand_sorter_kernel<<<n_blocks, BLOCK, 0, stream>>>(X, out, n_frames);
}

// Round 8
// 236.256 us; speedup vs baseline: 1.0375x; 1.0221x over previous
//
#include <hip/hip_runtime.h>
#include <stdint.h>

constexpr int FRAME_LEN = 130;   // floats per frame
constexpr int HALF      = 65;    // floats per hand block
constexpr int BLOCK     = 256;   // threads per block
constexpr int FPB       = 32;    // frames per block
constexpr int CHUNK_F   = FPB * FRAME_LEN;   // 4160 floats
constexpr int CHUNK_V4  = CHUNK_F / 4;       // 1040 vec4 = 4*256 + 16

#define GLOBAL_AS __attribute__((address_space(1)))
#define LDS_AS    __attribute__((address_space(3)))

// frame = idx / 130 for idx < 7825 via magic multiply
__device__ __forceinline__ int div130(int idx) {
    return (int)(((unsigned)idx * 8067u) >> 20);
}

__device__ __forceinline__ bool skip_pred(float h0, float p0, float h1, float p1) {
    const bool nan0 = (h0 != h0);
    const bool nan1 = (h1 != h1);
    const bool no_nan = !nan0 && !nan1;
    const bool eq = (h0 == h1);
    return (h1 > h0) ||
           (nan0 && nan1) ||
           (nan0 && (h1 == 1.0f)) ||
           (nan1 && (h0 == 0.0f)) ||
           (no_nan && eq && (h0 == 0.0f) && (p0 > p1)) ||
           (no_nan && eq && (h0 == 1.0f) && (p0 < p1));
}

__global__ __launch_bounds__(BLOCK, 8)   // low VGPR, 8 blocks/CU (LDS 16.6KB -> fits)
void hand_sorter_kernel(const float* __restrict__ X, float* __restrict__ out,
                        int n_frames) {
    __shared__ float s_buf[CHUNK_F];

    const int t = threadIdx.x;
    const long long frame0 = (long long)blockIdx.x * FPB;
    const long long rem = (long long)n_frames - frame0;
    const int frames_here = rem < (long long)FPB ? (int)rem : FPB;
    const long long base = frame0 * (long long)FRAME_LEN;
    const float* __restrict__ Xb = X + base;
    float* __restrict__ Ob = out + base;

    if (frames_here == FPB) {
        // ---- Phase 1: async DMA staging, global -> LDS, zero data VGPRs ----
        // Wave-uniform LDS base + lane*16B (HW rule); source is per-lane.
        // Identity layout, addresses independent of the skip mask, so all
        // 4(+1) DMA ops issue back-to-back into the global_load_lds queue.
        const int wbase = t & ~63;            // wave-uniform lane-0 vec4 index
#pragma unroll
        for (int k = 0; k < 4; ++k) {
            const float* src = Xb + 4 * (k * 256 + t);
            float* dst = s_buf + 4 * (k * 256 + wbase);
            __builtin_amdgcn_global_load_lds(
                (const GLOBAL_AS uint32_t*)src, (LDS_AS uint32_t*)dst, 16, 0, 0);
        }
        if (t < CHUNK_V4 - 1024) {            // tail 16 vec4s, wave 0 lanes 0..15
            const float* src = Xb + 4 * (1024 + t);
            float* dst = s_buf + 4 * 1024;    // wave-uniform
            __builtin_amdgcn_global_load_lds(
                (const GLOBAL_AS uint32_t*)src, (LDS_AS uint32_t*)dst, 16, 0, 0);
        }
        __syncthreads();                      // vmcnt(0) drain + barrier

        // ---- Phase 2: skip mask from LDS headers (per-wave, no 2nd barrier)
        const int lane = t & 63;
        bool pred = false;
        if (lane < FPB) {
            const float* fr = s_buf + lane * FRAME_LEN;
            pred = skip_pred(fr[0], fr[1], fr[HALF], fr[HALF + 1]);
        }
        const unsigned mask = (unsigned)__ballot(pred);

        // ---- Phase 3: branch-free LDS gather, aligned float4 stores ----
        float4* __restrict__ Ov = (float4*)Ob;
#pragma unroll
        for (int k = 0; k < 4; ++k) {
            const int i = t + k * 256;
            const int idx = 4 * i;
            float4 v;
            float* vp = (float*)&v;
#pragma unroll
            for (int e = 0; e < 4; ++e) {
                const int ide = idx + e;
                const int fl = div130(ide);
                const int jj = ide - fl * FRAME_LEN;
                int sj = jj + (((mask >> fl) & 1u) ? 0 : HALF);
                if (sj >= FRAME_LEN) sj -= FRAME_LEN;
                vp[e] = s_buf[fl * FRAME_LEN + sj];
            }
            Ov[i] = v;
        }
        if (t < CHUNK_V4 - 1024) {
            const int i = t + 1024;
            const int idx = 4 * i;
            float4 v;
            float* vp = (float*)&v;
#pragma unroll
            for (int e = 0; e < 4; ++e) {
                const int ide = idx + e;
                const int fl = div130(ide);
                const int jj = ide - fl * FRAME_LEN;
                int sj = jj + (((mask >> fl) & 1u) ? 0 : HALF);
                if (sj >= FRAME_LEN) sj -= FRAME_LEN;
                vp[e] = s_buf[fl * FRAME_LEN + sj];
            }
            Ov[i] = v;
        }
    } else {
        // ---- generic tail path (never taken for bench shape) ----
        const int nf = frames_here * FRAME_LEN;
        for (int i = t; i < nf; i += BLOCK) {
            const int fle = div130(i);
            const int je  = i - fle * FRAME_LEN;
            const float* fr = Xb + fle * FRAME_LEN;
            const bool sk = skip_pred(fr[0], fr[1], fr[HALF], fr[HALF + 1]);
            int sj = je + (sk ? 0 : (je < HALF ? HALF : -HALF));
            Ob[i] = fr[sj];
        }
    }
}

extern "C" void kernel_launch(void* const* d_in, const int* in_sizes, int n_in,
                              void* d_out, int out_size, void* d_ws, size_t ws_size,
                              hipStream_t stream) {
    const float* X = (const float*)d_in[0];
    float* out = (float*)d_out;
    const int n_frames = in_sizes[0] / FRAME_LEN;   // 262144
    const int n_blocks = (n_frames + FPB - 1) / FPB;
    hand_sorter_kernel<<<n_blocks, BLOCK, 0, stream>>>(X, out, n_frames);
}